// Round 11
// baseline (330.041 us; speedup 1.0000x reference)
//
#include <hip/hip_runtime.h>
#include <hip/hip_bf16.h>

namespace {

constexpr int HN  = 128;
constexpr int N0  = 80000, N1 = 60000, N2 = 45000;
constexpr int CIN = 64;
constexpr int E0  = 1280000, E1 = 360000, E2 = 315000;

constexpr int BSHIFT = 6;                 // 64 dst nodes per bucket
constexpr int BMASK  = 63;
constexpr int NBKT0  = (N0 + 63) / 64;    // 1250
constexpr int NBKT1  = (N1 + 63) / 64;    // 938
constexpr int CHUNK  = 8192;              // edges per partition block
constexpr int NBLK0  = (E0 + CHUNK - 1) / CHUNK;  // 157
constexpr int NBLK1  = (E1 + CHUNK - 1) / CHUNK;  // 44
constexpr int SRCCAP = 2560;              // LDS staging per bucket

using short8  = __attribute__((ext_vector_type(8))) short;
using short4v = __attribute__((ext_vector_type(4))) short;
using f32x4   = __attribute__((ext_vector_type(4))) float;

__device__ inline ushort f2bf(float f) {
    uint u = __float_as_uint(f);
    u += 0x7fffu + ((u >> 16) & 1u);
    return (ushort)(u >> 16);
}
__device__ inline float bf2f(ushort u) {
    return __uint_as_float(((uint)u) << 16);
}

__device__ inline int wave_scan_incl(int v, int lane) {
    #pragma unroll
    for (int d = 1; d < 64; d <<= 1) {
        int t = __shfl_up(v, d, 64);
        if (lane >= d) v += t;
    }
    return v;
}

// y=0: E2 histogram (fire-and-forget float atomics; integer-exact); y=1: weight transpose->bf16
__global__ __launch_bounds__(256) void setup_small(
    const int* __restrict__ ei2, float* __restrict__ cntE,
    const float* __restrict__ W0, const float* __restrict__ W1,
    const float* __restrict__ W2, const float* __restrict__ W3,
    const float* __restrict__ W4,
    ushort* __restrict__ T0, ushort* __restrict__ T1, ushort* __restrict__ T2,
    ushort* __restrict__ T3, ushort* __restrict__ T4)
{
    int idx = blockIdx.x * 256 + threadIdx.x;
    if (blockIdx.y == 0) {
        if (idx < 2 * E2) unsafeAtomicAdd(&cntE[ei2[idx]], 1.0f);
    } else {
        if (idx >= CIN * HN + 4 * HN * HN) return;
        const float* W; ushort* T; int K, local;
        if (idx < CIN * HN) { W = W0; T = T0; K = CIN; local = idx; }
        else {
            int r = idx - CIN * HN;
            int m = r >> 14; local = r & 16383; K = HN;
            switch (m) { case 0: W = W1; T = T1; break; case 1: W = W2; T = T2; break;
                         case 2: W = W3; T = T3; break; default: W = W4; T = T4; break; }
        }
        int n = local / K, k = local - n * K;
        T[local] = f2bf(W[k * HN + n]);
    }
}

// per-(block,bucket) counts + bucket totals
__global__ __launch_bounds__(512) void count_pass(
    const int* __restrict__ ei0, const int* __restrict__ ei1,
    int* __restrict__ blkcnt, int* __restrict__ bkttot)
{
    __shared__ int cnt[NBKT0];
    int b = blockIdx.x;
    const int* dst; int E, NBKT, bl, coff, toff;
    if (b < NBLK0) { dst = ei0 + E0; E = E0; NBKT = NBKT0; bl = b; coff = 0; toff = 0; }
    else { dst = ei1 + E1; E = E1; NBKT = NBKT1; bl = b - NBLK0; coff = NBLK0 * NBKT0; toff = NBKT0; }
    int tid = threadIdx.x;
    for (int q = tid; q < NBKT; q += 512) cnt[q] = 0;
    __syncthreads();
    int base = bl * CHUNK;
    #pragma unroll 4
    for (int it = 0; it < CHUNK / 512; ++it) {
        int e = base + it * 512 + tid;
        if (e < E) atomicAdd(&cnt[dst[e] >> BSHIFT], 1);
    }
    __syncthreads();
    for (int q = tid; q < NBKT; q += 512) {
        int c = cnt[q];
        blkcnt[coff + bl * NBKT + q] = c;
        if (c) atomicAdd(&bkttot[toff + q], c);
    }
}

// exclusive scan of bucket totals per level (+ sentinel)
__global__ void scanB(const int* __restrict__ bkttot, int* __restrict__ bktbase) {
    int seg = blockIdx.x;
    int n = seg ? NBKT1 : NBKT0;
    const int* src = bkttot + (seg ? NBKT0 : 0);
    int* dst = bktbase + (seg ? NBKT0 + 1 : 0);
    int lane = threadIdx.x;
    int carry = 0;
    for (int base = 0; base < n; base += 64) {
        int v = (base + lane < n) ? src[base + lane] : 0;
        int inc = wave_scan_incl(v, lane);
        if (base + lane < n) dst[base + lane] = carry + inc - v;
        carry += __shfl(inc, 63, 64);
    }
    if (lane == 0) dst[n] = carry;
}

// per-bucket scan over blocks -> absolute output cursor per (block,bucket)
__global__ void scanC(const int* __restrict__ blkcnt, const int* __restrict__ bktbase,
                      int* __restrict__ blkoff)
{
    int qg = blockIdx.x;
    int NBKT, NBLK, coff, q, boff;
    if (qg < NBKT0) { NBKT = NBKT0; NBLK = NBLK0; coff = 0; q = qg; boff = 0; }
    else { NBKT = NBKT1; NBLK = NBLK1; coff = NBLK0 * NBKT0; q = qg - NBKT0; boff = NBKT0 + 1; }
    int lane = threadIdx.x;
    int basev = bktbase[boff + q];
    int carry = 0;
    for (int base = 0; base < NBLK; base += 64) {
        int b = base + lane;
        int v = (b < NBLK) ? blkcnt[coff + b * NBKT + q] : 0;
        int inc = wave_scan_incl(v, lane);
        if (b < NBLK) blkoff[coff + b * NBKT + q] = basev + carry + inc - v;
        carry += __shfl(inc, 63, 64);
    }
}

// LDS-staged radix partition: pairs[slot] = src | (dst&63)<<17, grouped by dst>>6
__global__ __launch_bounds__(512) void partition_pass(
    const int* __restrict__ ei0, const int* __restrict__ ei1,
    const int* __restrict__ blkoff,
    int* __restrict__ pairs0, int* __restrict__ pairs1)
{
    __shared__ int off[NBKT0 + 1];
    __shared__ int cur[NBKT0];
    __shared__ int gb2[NBKT0];
    __shared__ int lpk[CHUNK];
    __shared__ int lga[CHUNK];
    __shared__ int wpart[8];
    int b = blockIdx.x;
    const int* src; const int* dst; int* pairs; int E, NBKT, bl, coff;
    if (b < NBLK0) { src = ei0; dst = ei0 + E0; pairs = pairs0; E = E0; NBKT = NBKT0; bl = b; coff = 0; }
    else { src = ei1; dst = ei1 + E1; pairs = pairs1; E = E1; NBKT = NBKT1; bl = b - NBLK0; coff = NBLK0 * NBKT0; }
    int tid = threadIdx.x;
    for (int q = tid; q < NBKT; q += 512) cur[q] = 0;
    __syncthreads();
    int base = bl * CHUNK;
    #pragma unroll 4
    for (int it = 0; it < CHUNK / 512; ++it) {
        int e = base + it * 512 + tid;
        if (e < E) atomicAdd(&cur[dst[e] >> BSHIFT], 1);
    }
    __syncthreads();
    {
        int carry = 0;
        int lane = tid & 63, w = tid >> 6;
        for (int bb = 0; bb < NBKT; bb += 512) {
            int v = (bb + tid < NBKT) ? cur[bb + tid] : 0;
            int inc = wave_scan_incl(v, lane);
            __syncthreads();
            if (lane == 63) wpart[w] = inc;
            __syncthreads();
            int woff = 0, tot = 0;
            #pragma unroll
            for (int k = 0; k < 8; ++k) { if (k < w) woff += wpart[k]; tot += wpart[k]; }
            if (bb + tid < NBKT) off[bb + tid] = carry + woff + inc - v;
            carry += tot;
        }
        if (tid == 0) off[NBKT] = carry;
    }
    __syncthreads();
    for (int q = tid; q < NBKT; q += 512) {
        cur[q] = off[q];
        gb2[q] = blkoff[coff + bl * NBKT + q] - off[q];
    }
    __syncthreads();
    #pragma unroll 4
    for (int it = 0; it < CHUNK / 512; ++it) {
        int e = base + it * 512 + tid;
        if (e < E) {
            int d = dst[e];
            int q = d >> BSHIFT;
            int s = atomicAdd(&cur[q], 1);
            lpk[s] = src[e] | ((d & BMASK) << 17);
            lga[s] = gb2[q] + s;
        }
    }
    __syncthreads();
    int cnt_tot = min(CHUNK, E - base);
    for (int s = tid; s < cnt_tot; s += 512)
        pairs[lga[s]] = lpk[s];
}

// per-bucket counting sort: pairs -> node-ordered src lists (in place) + noff[N+1].
// Level-0 blocks also emit xs = bf16(dinv0*x).
__global__ __launch_bounds__(256) void sort_pass(
    int* __restrict__ pairs0, int* __restrict__ pairs1,
    const int* __restrict__ bktbase,
    int* __restrict__ noff0, int* __restrict__ noff1,
    const float* __restrict__ x, ushort* __restrict__ xs)
{
    __shared__ int lpk[SRCCAP];
    __shared__ int cnt[64];
    __shared__ int cur[64];
    __shared__ float dvl[64];
    int qg = blockIdx.x;
    int* pairs; int* noff; int q, boff, N, nbkt;
    bool lvl0 = qg < NBKT0;
    if (lvl0) { pairs = pairs0; noff = noff0; q = qg; boff = 0; N = N0; nbkt = NBKT0; }
    else { pairs = pairs1; noff = noff1; q = qg - NBKT0; boff = NBKT0 + 1; N = N1; nbkt = NBKT1; }
    int tid = threadIdx.x;
    if (tid < 64) cnt[tid] = 0;
    __syncthreads();
    int s0 = bktbase[boff + q], s1 = bktbase[boff + q + 1];
    int m = min(s1 - s0, SRCCAP);
    for (int s = tid; s < m; s += 256) {
        int pk = pairs[s0 + s];
        lpk[s] = pk;
        atomicAdd(&cnt[(pk >> 17) & BMASK], 1);
    }
    __syncthreads();
    if (tid < 64) {
        int v = cnt[tid];
        int inc = wave_scan_incl(v, tid);
        cur[tid] = inc - v;
        dvl[tid] = rsqrtf((float)v + 2.0f);
        int i = q * 64 + tid;
        if (i < N) noff[i] = s0 + inc - v;
        if (q == nbkt - 1 && tid == 0) noff[N] = s1;
    }
    __syncthreads();
    for (int s = tid; s < m; s += 256) {
        int pk = lpk[s];
        int p = atomicAdd(&cur[(pk >> 17) & BMASK], 1);
        pairs[s0 + p] = pk & 0x1FFFF;
    }
    if (lvl0) {
        for (int idx = tid; idx < 64 * 64; idx += 256) {
            int nl = idx >> 6, col = idx & 63;
            size_t i = (size_t)q * 64 + nl;          // N0 == 1250*64
            xs[i * CIN + col] = f2bf(dvl[nl] * x[i * CIN + col]);
        }
    }
}

// ---------------------------------------------------------------------------
// Fused L0 (256 thr, 64-row tile): agg(xs, ei0) -> gemm0(W0,+b,relu) -> gemm1(W1,*dinv1)
// grid = N1/64 blocks (h0 rows >= N1 are discarded by the reference pooling).
__global__ __launch_bounds__(256) void fused_l0(
    const int* __restrict__ noff0, const int* __restrict__ csr0,
    const ushort* __restrict__ xs,
    const ushort* __restrict__ Wt0, const float* __restrict__ b0,
    const ushort* __restrict__ Wt1, const int* __restrict__ noff1,
    ushort* __restrict__ Tout)
{
    __shared__ ushort al[64 * 64];    // agg tile (K=64), swizzled 16B groups
    __shared__ ushort hl[64 * 128];   // h0 tile (K=128), swizzled 16B groups
    const int tid = threadIdx.x;
    const int rowbase = blockIdx.x * 64;

    // ---- gather phase (16 lanes per node, 4 cols each), unroll 8 ----
    {
        const int grp = tid >> 4, ln = tid & 15;
        for (int dd = grp; dd < 64; dd += 16) {
            int i = rowbase + dd;
            short4v o = {0, 0, 0, 0};
            if (i < N1) {
                int e = noff0[i], e1 = noff0[i + 1];
                float dv = rsqrtf((float)(e1 - e) + 2.f);
                float acc[4] = {0.f, 0.f, 0.f, 0.f};
                for (; e + 8 <= e1; e += 8) {
                    int s[8];
                    #pragma unroll
                    for (int k = 0; k < 8; ++k) s[k] = csr0[e + k];
                    short4v v[8];
                    #pragma unroll
                    for (int k = 0; k < 8; ++k)
                        v[k] = *reinterpret_cast<const short4v*>(xs + (size_t)s[k] * CIN + ln * 4);
                    #pragma unroll
                    for (int j = 0; j < 4; ++j)
                        acc[j] += ((bf2f((ushort)v[0][j]) + bf2f((ushort)v[1][j]))
                                 + (bf2f((ushort)v[2][j]) + bf2f((ushort)v[3][j])))
                                + ((bf2f((ushort)v[4][j]) + bf2f((ushort)v[5][j]))
                                 + (bf2f((ushort)v[6][j]) + bf2f((ushort)v[7][j])));
                }
                for (; e < e1; ++e) {
                    int s = csr0[e];
                    short4v v = *reinterpret_cast<const short4v*>(xs + (size_t)s * CIN + ln * 4);
                    #pragma unroll
                    for (int j = 0; j < 4; ++j) acc[j] += bf2f((ushort)v[j]);
                }
                short4v t4 = *reinterpret_cast<const short4v*>(xs + (size_t)i * CIN + ln * 4);
                #pragma unroll
                for (int j = 0; j < 4; ++j)
                    o[j] = (short)f2bf(dv * (acc[j] + 2.f * bf2f((ushort)t4[j])));
            }
            int g = ln >> 1, sub = ln & 1;
            *reinterpret_cast<short4v*>(
                &al[dd * 64 + (((g ^ (dd & 7)) << 3) | (sub << 2))]) = o;
        }
    }
    __syncthreads();

    const int wid = tid >> 6, lane = tid & 63, l15 = lane & 15, lhi = lane >> 4;
    const int arow = wid * 16 + l15;

    // ---- gemm0: h0 = relu(agg @ W0 + b0) -> hl ----
    {
        short8 a0[2];
        #pragma unroll
        for (int kb = 0; kb < 2; ++kb) {
            int g = kb * 4 + lhi;
            a0[kb] = *reinterpret_cast<const short8*>(&al[arow * 64 + ((g ^ (arow & 7)) << 3)]);
        }
        f32x4 c0[8];
        #pragma unroll
        for (int nf = 0; nf < 8; ++nf) c0[nf] = f32x4{0.f, 0.f, 0.f, 0.f};
        #pragma unroll
        for (int nf = 0; nf < 8; ++nf) {
            #pragma unroll
            for (int kb = 0; kb < 2; ++kb) {
                short8 b = *reinterpret_cast<const short8*>(
                    &Wt0[(size_t)(nf * 16 + l15) * CIN + kb * 32 + lhi * 8]);
                c0[nf] = __builtin_amdgcn_mfma_f32_16x16x32_bf16(a0[kb], b, c0[nf], 0, 0, 0);
            }
        }
        #pragma unroll
        for (int j = 0; j < 4; ++j) {
            int mrow = wid * 16 + lhi * 4 + j;
            #pragma unroll
            for (int nf = 0; nf < 8; ++nf) {
                int n = nf * 16 + l15;
                float v = fmaxf(c0[nf][j] + b0[n], 0.f);
                int g = n >> 3, sub = n & 7;
                hl[mrow * 128 + (((g ^ (mrow & 15)) << 3) | sub)] = f2bf(v);
            }
        }
    }
    __syncthreads();

    // ---- gemm1: T = dinv1 * (h0 @ W1) ----
    short8 a1[4];
    #pragma unroll
    for (int kb = 0; kb < 4; ++kb) {
        int g = kb * 4 + lhi;
        a1[kb] = *reinterpret_cast<const short8*>(&hl[arow * 128 + ((g ^ (arow & 15)) << 3)]);
    }
    f32x4 c1[8];
    #pragma unroll
    for (int nf = 0; nf < 8; ++nf) c1[nf] = f32x4{0.f, 0.f, 0.f, 0.f};
    #pragma unroll
    for (int nf = 0; nf < 8; ++nf) {
        #pragma unroll
        for (int kb = 0; kb < 4; ++kb) {
            short8 b = *reinterpret_cast<const short8*>(
                &Wt1[(size_t)(nf * 16 + l15) * HN + kb * 32 + lhi * 8]);
            c1[nf] = __builtin_amdgcn_mfma_f32_16x16x32_bf16(a1[kb], b, c1[nf], 0, 0, 0);
        }
    }
    #pragma unroll
    for (int j = 0; j < 4; ++j) {
        int m = rowbase + wid * 16 + lhi * 4 + j;
        if (m >= N1) continue;
        float d = rsqrtf((float)(noff1[m + 1] - noff1[m]) + 2.f);
        #pragma unroll
        for (int nf = 0; nf < 8; ++nf) {
            int n = nf * 16 + l15;
            Tout[(size_t)m * HN + n] = f2bf(c1[nf][j] * d);
        }
    }
}

// ---------------------------------------------------------------------------
// Fused gather+GEMM (256 thr, 64-row tile, K=128): h = relu?(dv*(agg T + 2T) + gbias)
// per row (<NG, else 0), then out = [h @ Wt (+ev*Wex) (+gemmbias)] (*dinv via snoff)
template<bool GBIAS, bool EXTRA, bool GEMMBIAS, bool SCALE, bool OUTF32>
__global__ __launch_bounds__(256) void fused_gg(
    const int* __restrict__ noff, const int* __restrict__ csr,
    const ushort* __restrict__ T,
    const float* __restrict__ gbias, int NG,
    const float* __restrict__ extraVal, int extraLimit, const float* __restrict__ Wex,
    const ushort* __restrict__ Wt, const float* __restrict__ gemmbias,
    const int* __restrict__ snoff,
    void* __restrict__ dstv, int M)
{
    __shared__ ushort hl[64 * 128];
    const int tid = threadIdx.x;
    const int rowbase = blockIdx.x * 64;

    // ---- gather phase (16 lanes per node, 8 cols each), unroll 8 ----
    {
        const int grp = tid >> 4, ln = tid & 15;
        for (int dd = grp; dd < 64; dd += 16) {
            int i = rowbase + dd;
            short8 o = {0, 0, 0, 0, 0, 0, 0, 0};
            if (i < NG) {
                int e = noff[i], e1 = noff[i + 1];
                float dv = rsqrtf((float)(e1 - e) + 2.f);
                float acc[8] = {0.f, 0.f, 0.f, 0.f, 0.f, 0.f, 0.f, 0.f};
                for (; e + 8 <= e1; e += 8) {
                    int s[8];
                    #pragma unroll
                    for (int k = 0; k < 8; ++k) s[k] = csr[e + k];
                    short8 v[8];
                    #pragma unroll
                    for (int k = 0; k < 8; ++k)
                        v[k] = *reinterpret_cast<const short8*>(T + (size_t)s[k] * HN + ln * 8);
                    #pragma unroll
                    for (int j = 0; j < 8; ++j)
                        acc[j] += ((bf2f((ushort)v[0][j]) + bf2f((ushort)v[1][j]))
                                 + (bf2f((ushort)v[2][j]) + bf2f((ushort)v[3][j])))
                                + ((bf2f((ushort)v[4][j]) + bf2f((ushort)v[5][j]))
                                 + (bf2f((ushort)v[6][j]) + bf2f((ushort)v[7][j])));
                }
                for (; e < e1; ++e) {
                    int s = csr[e];
                    short8 v = *reinterpret_cast<const short8*>(T + (size_t)s * HN + ln * 8);
                    #pragma unroll
                    for (int j = 0; j < 8; ++j) acc[j] += bf2f((ushort)v[j]);
                }
                short8 t8 = *reinterpret_cast<const short8*>(T + (size_t)i * HN + ln * 8);
                #pragma unroll
                for (int j = 0; j < 8; ++j) {
                    float v = dv * (acc[j] + 2.f * bf2f((ushort)t8[j]));
                    if (GBIAS) v = fmaxf(v + gbias[ln * 8 + j], 0.f);
                    o[j] = (short)f2bf(v);
                }
            }
            *reinterpret_cast<short8*>(&hl[dd * 128 + ((ln ^ (dd & 15)) << 3)]) = o;
        }
    }
    __syncthreads();

    // ---- GEMM phase: 4 waves, each 16 rows x 128 cols ----
    const int wid = tid >> 6, lane = tid & 63, l15 = lane & 15, lhi = lane >> 4;
    const int arow = wid * 16 + l15;
    short8 a[4];
    #pragma unroll
    for (int kb = 0; kb < 4; ++kb) {
        int g = kb * 4 + lhi;
        a[kb] = *reinterpret_cast<const short8*>(&hl[arow * 128 + ((g ^ (arow & 15)) << 3)]);
    }
    f32x4 acc[8];
    #pragma unroll
    for (int nf = 0; nf < 8; ++nf) acc[nf] = f32x4{0.f, 0.f, 0.f, 0.f};
    #pragma unroll
    for (int nf = 0; nf < 8; ++nf) {
        #pragma unroll
        for (int kb = 0; kb < 4; ++kb) {
            short8 b = *reinterpret_cast<const short8*>(
                &Wt[(size_t)(nf * 16 + l15) * HN + kb * 32 + lhi * 8]);
            acc[nf] = __builtin_amdgcn_mfma_f32_16x16x32_bf16(a[kb], b, acc[nf], 0, 0, 0);
        }
    }
    #pragma unroll
    for (int j = 0; j < 4; ++j) {
        int m = rowbase + wid * 16 + lhi * 4 + j;
        if (m >= M) continue;
        float ev = 0.f, d = 1.f;
        if (EXTRA) ev = (m < extraLimit) ? extraVal[m] : 0.f;
        if (SCALE) d = rsqrtf((float)(snoff[m + 1] - snoff[m]) + 2.f);
        #pragma unroll
        for (int nf = 0; nf < 8; ++nf) {
            int n = nf * 16 + l15;
            float v = acc[nf][j];
            if (EXTRA)    v += ev * Wex[n];
            if (GEMMBIAS) v += gemmbias[n];
            if (SCALE)    v *= d;
            if (OUTF32) ((float*)dstv)[(size_t)m * HN + n] = v;
            else        ((ushort*)dstv)[(size_t)m * HN + n] = f2bf(v);
        }
    }
}

inline int cdiv(int a, int b) { return (a + b - 1) / b; }

} // namespace

extern "C" void kernel_launch(void* const* d_in, const int* in_sizes, int n_in,
                              void* d_out, int out_size, void* d_ws, size_t ws_size,
                              hipStream_t stream)
{
    const float* x       = (const float*)d_in[0];
    const float* W_down0 = (const float*)d_in[2];
    const float* b_down0 = (const float*)d_in[3];
    const float* W_down1 = (const float*)d_in[4];
    const float* b_down1 = (const float*)d_in[5];
    const float* W_up0   = (const float*)d_in[6];
    const float* b_up0   = (const float*)d_in[7];
    const float* W_up1   = (const float*)d_in[8];
    const float* b_up1   = (const float*)d_in[9];
    const float* W_lin   = (const float*)d_in[10];
    const float* b_lin   = (const float*)d_in[11];
    const int*   ei0     = (const int*)d_in[12];
    const int*   ei1     = (const int*)d_in[13];
    const int*   ei2     = (const int*)d_in[14];

    char* ws = (char*)d_ws;
    size_t o = 0;
    auto carve = [&](size_t bytes) { void* p = ws + o; o += (bytes + 15) & ~size_t(15); return p; };

    ushort* X     = (ushort*)carve((size_t)N0 * HN * 2);   // hosts xs during setup/L0
    ushort* T     = (ushort*)carve((size_t)N0 * HN * 2);
    ushort* Wt0   = (ushort*)carve((size_t)HN * CIN * 2);
    ushort* Wt1   = (ushort*)carve((size_t)HN * HN * 2);
    ushort* Wt2   = (ushort*)carve((size_t)HN * HN * 2);
    ushort* Wt3   = (ushort*)carve((size_t)HN * HN * 2);
    ushort* Wt4   = (ushort*)carve((size_t)HN * HN * 2);
    int*    pairs0 = (int*)carve((size_t)E0 * 4);
    int*    pairs1 = (int*)carve((size_t)E1 * 4);
    int*    blkcnt = (int*)carve((size_t)(NBLK0 * NBKT0 + NBLK1 * NBKT1) * 4);
    int*    blkoff = (int*)carve((size_t)(NBLK0 * NBKT0 + NBLK1 * NBKT1) * 4);
    int*    bktbase = (int*)carve((size_t)(NBKT0 + NBKT1 + 2) * 4);
    int*    noff0 = (int*)carve((size_t)(N0 + 1) * 4);
    int*    noff1 = (int*)carve((size_t)(N1 + 1) * 4);
    // contiguous zero block
    size_t zero_off = o;
    int*    bkttot = (int*)carve((size_t)(NBKT0 + NBKT1) * 4);
    float*  cntE   = (float*)carve((size_t)N2 * 4);
    size_t zero_bytes = o - zero_off;

    ushort* xs = X;   // xs [N0 x 64] bf16 lives in X until F2 overwrites it

    hipMemsetAsync(ws + zero_off, 0, zero_bytes, stream);

    // ---- setup ----
    setup_small<<<dim3(cdiv(2 * E2, 256), 2), 256, 0, stream>>>(
        ei2, cntE, W_down0, W_down1, W_up0, W_up1, W_lin, Wt0, Wt1, Wt2, Wt3, Wt4);
    count_pass<<<NBLK0 + NBLK1, 512, 0, stream>>>(ei0, ei1, blkcnt, bkttot);
    scanB<<<2, 64, 0, stream>>>(bkttot, bktbase);
    scanC<<<NBKT0 + NBKT1, 64, 0, stream>>>(blkcnt, bktbase, blkoff);
    partition_pass<<<NBLK0 + NBLK1, 512, 0, stream>>>(ei0, ei1, blkoff, pairs0, pairs1);
    sort_pass<<<NBKT0 + NBKT1, 256, 0, stream>>>(pairs0, pairs1, bktbase,
                                                 noff0, noff1, x, xs);

    // ---- F01: xs --agg0--> gemm0(relu) --> gemm1(*dinv1) --> T[0:N1] ----
    fused_l0<<<cdiv(N1, 64), 256, 0, stream>>>(
        noff0, pairs0, xs, Wt0, b_down0, Wt1, noff1, T);

    // ---- F2: T --agg1(relu,b_down1; rows<N2)--> gemm(W_up0 + cntE*Wex, *dinv1) --> X ----
    fused_gg<true, true, false, true, false><<<cdiv(N1, 64), 256, 0, stream>>>(
        noff1, pairs1, T, b_down1, N2,
        cntE, N2, W_up0 + 128 * HN, Wt2, nullptr, noff1, X, N1);

    // ---- F3: X --agg1(relu,b_up0; rows<N1)--> gemm(W_up1 + cntE*Wex, *dinv0) --> T ----
    fused_gg<true, true, false, true, false><<<cdiv(N0, 64), 256, 0, stream>>>(
        noff1, pairs1, X, b_up0, N1,
        cntE, N2, W_up1 + 128 * HN, Wt3, nullptr, noff0, T, N0);

    // ---- F4: T --agg0(relu,b_up1)--> gemm(W_lin + b_lin) --> d_out (f32) ----
    fused_gg<true, false, true, false, true><<<cdiv(N0, 64), 256, 0, stream>>>(
        noff0, pairs0, T, b_up1, N0,
        nullptr, 0, nullptr, Wt4, b_lin, nullptr, d_out, N0);
}

// Round 12
// 291.461 us; speedup vs baseline: 1.1324x; 1.1324x over previous
//
#include <hip/hip_runtime.h>
#include <hip/hip_bf16.h>

namespace {

constexpr int HN  = 128;
constexpr int N0  = 80000, N1 = 60000, N2 = 45000;
constexpr int CIN = 64;
constexpr int E0  = 1280000, E1 = 360000, E2 = 315000;

constexpr int BSHIFT = 6;                 // 64 dst nodes per bucket
constexpr int BMASK  = 63;
constexpr int NBKT0  = (N0 + 63) / 64;    // 1250
constexpr int NBKT1  = (N1 + 63) / 64;    // 938
constexpr int CHUNK  = 8192;              // edges per partition block
constexpr int NBLK0  = (E0 + CHUNK - 1) / CHUNK;  // 157
constexpr int NBLK1  = (E1 + CHUNK - 1) / CHUNK;  // 44
constexpr int SRCCAP = 2560;              // LDS staging per bucket

using short8  = __attribute__((ext_vector_type(8))) short;
using short4v = __attribute__((ext_vector_type(4))) short;
using f32x4   = __attribute__((ext_vector_type(4))) float;

__device__ inline ushort f2bf(float f) {
    uint u = __float_as_uint(f);
    u += 0x7fffu + ((u >> 16) & 1u);
    return (ushort)(u >> 16);
}
__device__ inline float bf2f(ushort u) {
    return __uint_as_float(((uint)u) << 16);
}

__device__ inline int wave_scan_incl(int v, int lane) {
    #pragma unroll
    for (int d = 1; d < 64; d <<= 1) {
        int t = __shfl_up(v, d, 64);
        if (lane >= d) v += t;
    }
    return v;
}

// y=0: E2 histogram (fire-and-forget float atomics; integer-exact); y=1: weight transpose->bf16
__global__ __launch_bounds__(256) void setup_small(
    const int* __restrict__ ei2, float* __restrict__ cntE,
    const float* __restrict__ W0, const float* __restrict__ W1,
    const float* __restrict__ W2, const float* __restrict__ W3,
    const float* __restrict__ W4,
    ushort* __restrict__ T0, ushort* __restrict__ T1, ushort* __restrict__ T2,
    ushort* __restrict__ T3, ushort* __restrict__ T4)
{
    int idx = blockIdx.x * 256 + threadIdx.x;
    if (blockIdx.y == 0) {
        if (idx < 2 * E2) unsafeAtomicAdd(&cntE[ei2[idx]], 1.0f);
    } else {
        if (idx >= CIN * HN + 4 * HN * HN) return;
        const float* W; ushort* T; int K, local;
        if (idx < CIN * HN) { W = W0; T = T0; K = CIN; local = idx; }
        else {
            int r = idx - CIN * HN;
            int m = r >> 14; local = r & 16383; K = HN;
            switch (m) { case 0: W = W1; T = T1; break; case 1: W = W2; T = T2; break;
                         case 2: W = W3; T = T3; break; default: W = W4; T = T4; break; }
        }
        int n = local / K, k = local - n * K;
        T[local] = f2bf(W[k * HN + n]);
    }
}

// per-(block,bucket) counts + bucket totals
__global__ __launch_bounds__(512) void count_pass(
    const int* __restrict__ ei0, const int* __restrict__ ei1,
    int* __restrict__ blkcnt, int* __restrict__ bkttot)
{
    __shared__ int cnt[NBKT0];
    int b = blockIdx.x;
    const int* dst; int E, NBKT, bl, coff, toff;
    if (b < NBLK0) { dst = ei0 + E0; E = E0; NBKT = NBKT0; bl = b; coff = 0; toff = 0; }
    else { dst = ei1 + E1; E = E1; NBKT = NBKT1; bl = b - NBLK0; coff = NBLK0 * NBKT0; toff = NBKT0; }
    int tid = threadIdx.x;
    for (int q = tid; q < NBKT; q += 512) cnt[q] = 0;
    __syncthreads();
    int base = bl * CHUNK;
    #pragma unroll 4
    for (int it = 0; it < CHUNK / 512; ++it) {
        int e = base + it * 512 + tid;
        if (e < E) atomicAdd(&cnt[dst[e] >> BSHIFT], 1);
    }
    __syncthreads();
    for (int q = tid; q < NBKT; q += 512) {
        int c = cnt[q];
        blkcnt[coff + bl * NBKT + q] = c;
        if (c) atomicAdd(&bkttot[toff + q], c);
    }
}

// exclusive scan of bucket totals per level (+ sentinel)
__global__ void scanB(const int* __restrict__ bkttot, int* __restrict__ bktbase) {
    int seg = blockIdx.x;
    int n = seg ? NBKT1 : NBKT0;
    const int* src = bkttot + (seg ? NBKT0 : 0);
    int* dst = bktbase + (seg ? NBKT0 + 1 : 0);
    int lane = threadIdx.x;
    int carry = 0;
    for (int base = 0; base < n; base += 64) {
        int v = (base + lane < n) ? src[base + lane] : 0;
        int inc = wave_scan_incl(v, lane);
        if (base + lane < n) dst[base + lane] = carry + inc - v;
        carry += __shfl(inc, 63, 64);
    }
    if (lane == 0) dst[n] = carry;
}

// per-bucket scan over blocks -> absolute output cursor per (block,bucket)
__global__ void scanC(const int* __restrict__ blkcnt, const int* __restrict__ bktbase,
                      int* __restrict__ blkoff)
{
    int qg = blockIdx.x;
    int NBKT, NBLK, coff, q, boff;
    if (qg < NBKT0) { NBKT = NBKT0; NBLK = NBLK0; coff = 0; q = qg; boff = 0; }
    else { NBKT = NBKT1; NBLK = NBLK1; coff = NBLK0 * NBKT0; q = qg - NBKT0; boff = NBKT0 + 1; }
    int lane = threadIdx.x;
    int basev = bktbase[boff + q];
    int carry = 0;
    for (int base = 0; base < NBLK; base += 64) {
        int b = base + lane;
        int v = (b < NBLK) ? blkcnt[coff + b * NBKT + q] : 0;
        int inc = wave_scan_incl(v, lane);
        if (b < NBLK) blkoff[coff + b * NBKT + q] = basev + carry + inc - v;
        carry += __shfl(inc, 63, 64);
    }
}

// LDS-staged radix partition: pairs[slot] = src | (dst&63)<<17, grouped by dst>>6
__global__ __launch_bounds__(512) void partition_pass(
    const int* __restrict__ ei0, const int* __restrict__ ei1,
    const int* __restrict__ blkoff,
    int* __restrict__ pairs0, int* __restrict__ pairs1)
{
    __shared__ int off[NBKT0 + 1];
    __shared__ int cur[NBKT0];
    __shared__ int gb2[NBKT0];
    __shared__ int lpk[CHUNK];
    __shared__ int lga[CHUNK];
    __shared__ int wpart[8];
    int b = blockIdx.x;
    const int* src; const int* dst; int* pairs; int E, NBKT, bl, coff;
    if (b < NBLK0) { src = ei0; dst = ei0 + E0; pairs = pairs0; E = E0; NBKT = NBKT0; bl = b; coff = 0; }
    else { src = ei1; dst = ei1 + E1; pairs = pairs1; E = E1; NBKT = NBKT1; bl = b - NBLK0; coff = NBLK0 * NBKT0; }
    int tid = threadIdx.x;
    for (int q = tid; q < NBKT; q += 512) cur[q] = 0;
    __syncthreads();
    int base = bl * CHUNK;
    #pragma unroll 4
    for (int it = 0; it < CHUNK / 512; ++it) {
        int e = base + it * 512 + tid;
        if (e < E) atomicAdd(&cur[dst[e] >> BSHIFT], 1);
    }
    __syncthreads();
    {
        int carry = 0;
        int lane = tid & 63, w = tid >> 6;
        for (int bb = 0; bb < NBKT; bb += 512) {
            int v = (bb + tid < NBKT) ? cur[bb + tid] : 0;
            int inc = wave_scan_incl(v, lane);
            __syncthreads();
            if (lane == 63) wpart[w] = inc;
            __syncthreads();
            int woff = 0, tot = 0;
            #pragma unroll
            for (int k = 0; k < 8; ++k) { if (k < w) woff += wpart[k]; tot += wpart[k]; }
            if (bb + tid < NBKT) off[bb + tid] = carry + woff + inc - v;
            carry += tot;
        }
        if (tid == 0) off[NBKT] = carry;
    }
    __syncthreads();
    for (int q = tid; q < NBKT; q += 512) {
        cur[q] = off[q];
        gb2[q] = blkoff[coff + bl * NBKT + q] - off[q];
    }
    __syncthreads();
    #pragma unroll 4
    for (int it = 0; it < CHUNK / 512; ++it) {
        int e = base + it * 512 + tid;
        if (e < E) {
            int d = dst[e];
            int q = d >> BSHIFT;
            int s = atomicAdd(&cur[q], 1);
            lpk[s] = src[e] | ((d & BMASK) << 17);
            lga[s] = gb2[q] + s;
        }
    }
    __syncthreads();
    int cnt_tot = min(CHUNK, E - base);
    for (int s = tid; s < cnt_tot; s += 512)
        pairs[lga[s]] = lpk[s];
}

// per-bucket counting sort: pairs -> node-ordered src lists (in place) + noff[N+1].
// Level-0 blocks also emit xs = bf16(dinv0*x).
__global__ __launch_bounds__(256) void sort_pass(
    int* __restrict__ pairs0, int* __restrict__ pairs1,
    const int* __restrict__ bktbase,
    int* __restrict__ noff0, int* __restrict__ noff1,
    const float* __restrict__ x, ushort* __restrict__ xs)
{
    __shared__ int lpk[SRCCAP];
    __shared__ int cnt[64];
    __shared__ int cur[64];
    __shared__ float dvl[64];
    int qg = blockIdx.x;
    int* pairs; int* noff; int q, boff, N, nbkt;
    bool lvl0 = qg < NBKT0;
    if (lvl0) { pairs = pairs0; noff = noff0; q = qg; boff = 0; N = N0; nbkt = NBKT0; }
    else { pairs = pairs1; noff = noff1; q = qg - NBKT0; boff = NBKT0 + 1; N = N1; nbkt = NBKT1; }
    int tid = threadIdx.x;
    if (tid < 64) cnt[tid] = 0;
    __syncthreads();
    int s0 = bktbase[boff + q], s1 = bktbase[boff + q + 1];
    int m = min(s1 - s0, SRCCAP);
    for (int s = tid; s < m; s += 256) {
        int pk = pairs[s0 + s];
        lpk[s] = pk;
        atomicAdd(&cnt[(pk >> 17) & BMASK], 1);
    }
    __syncthreads();
    if (tid < 64) {
        int v = cnt[tid];
        int inc = wave_scan_incl(v, tid);
        cur[tid] = inc - v;
        dvl[tid] = rsqrtf((float)v + 2.0f);
        int i = q * 64 + tid;
        if (i < N) noff[i] = s0 + inc - v;
        if (q == nbkt - 1 && tid == 0) noff[N] = s1;
    }
    __syncthreads();
    for (int s = tid; s < m; s += 256) {
        int pk = lpk[s];
        int p = atomicAdd(&cur[(pk >> 17) & BMASK], 1);
        pairs[s0 + p] = pk & 0x1FFFF;
    }
    if (lvl0) {
        for (int idx = tid; idx < 64 * 64; idx += 256) {
            int nl = idx >> 6, col = idx & 63;
            size_t i = (size_t)q * 64 + nl;          // N0 == 1250*64
            xs[i * CIN + col] = f2bf(dvl[nl] * x[i * CIN + col]);
        }
    }
}

// ---------------------------------------------------------------------------
// Fused L0 (256 thr, 64-row tile): agg(xs, ei0) -> gemm0(W0,+b,relu) -> gemm1(W1,*dinv1)
// grid = N1/64 blocks (h0 rows >= N1 are discarded by the reference pooling).
__global__ __launch_bounds__(256) void fused_l0(
    const int* __restrict__ noff0, const int* __restrict__ csr0,
    const ushort* __restrict__ xs,
    const ushort* __restrict__ Wt0, const float* __restrict__ b0,
    const ushort* __restrict__ Wt1, const int* __restrict__ noff1,
    ushort* __restrict__ Tout)
{
    __shared__ ushort al[64 * 64];    // agg tile (K=64), swizzled 16B groups
    __shared__ ushort hl[64 * 128];   // h0 tile (K=128), swizzled 16B groups
    const int tid = threadIdx.x;
    const int rowbase = blockIdx.x * 64;

    // ---- gather phase (16 lanes per node, 4 cols each) ----
    {
        const int grp = tid >> 4, ln = tid & 15;
        for (int dd = grp; dd < 64; dd += 16) {
            int i = rowbase + dd;
            short4v o = {0, 0, 0, 0};
            if (i < N1) {
                int e = noff0[i], e1 = noff0[i + 1];
                float dv = rsqrtf((float)(e1 - e) + 2.f);
                float acc[4] = {0.f, 0.f, 0.f, 0.f};
                for (; e + 4 <= e1; e += 4) {
                    int sa = csr0[e], sb = csr0[e + 1], sc = csr0[e + 2], sd = csr0[e + 3];
                    short4v va = *reinterpret_cast<const short4v*>(xs + (size_t)sa * CIN + ln * 4);
                    short4v vb = *reinterpret_cast<const short4v*>(xs + (size_t)sb * CIN + ln * 4);
                    short4v vc = *reinterpret_cast<const short4v*>(xs + (size_t)sc * CIN + ln * 4);
                    short4v vd = *reinterpret_cast<const short4v*>(xs + (size_t)sd * CIN + ln * 4);
                    #pragma unroll
                    for (int j = 0; j < 4; ++j)
                        acc[j] += (bf2f((ushort)va[j]) + bf2f((ushort)vb[j]))
                                + (bf2f((ushort)vc[j]) + bf2f((ushort)vd[j]));
                }
                for (; e < e1; ++e) {
                    int s = csr0[e];
                    short4v v = *reinterpret_cast<const short4v*>(xs + (size_t)s * CIN + ln * 4);
                    #pragma unroll
                    for (int j = 0; j < 4; ++j) acc[j] += bf2f((ushort)v[j]);
                }
                short4v t4 = *reinterpret_cast<const short4v*>(xs + (size_t)i * CIN + ln * 4);
                #pragma unroll
                for (int j = 0; j < 4; ++j)
                    o[j] = (short)f2bf(dv * (acc[j] + 2.f * bf2f((ushort)t4[j])));
            }
            int g = ln >> 1, sub = ln & 1;
            *reinterpret_cast<short4v*>(
                &al[dd * 64 + (((g ^ (dd & 7)) << 3) | (sub << 2))]) = o;
        }
    }
    __syncthreads();

    const int wid = tid >> 6, lane = tid & 63, l15 = lane & 15, lhi = lane >> 4;
    const int arow = wid * 16 + l15;

    // ---- gemm0: h0 = relu(agg @ W0 + b0) -> hl ----
    {
        short8 a0[2];
        #pragma unroll
        for (int kb = 0; kb < 2; ++kb) {
            int g = kb * 4 + lhi;
            a0[kb] = *reinterpret_cast<const short8*>(&al[arow * 64 + ((g ^ (arow & 7)) << 3)]);
        }
        f32x4 c0[8];
        #pragma unroll
        for (int nf = 0; nf < 8; ++nf) c0[nf] = f32x4{0.f, 0.f, 0.f, 0.f};
        #pragma unroll
        for (int nf = 0; nf < 8; ++nf) {
            #pragma unroll
            for (int kb = 0; kb < 2; ++kb) {
                short8 b = *reinterpret_cast<const short8*>(
                    &Wt0[(size_t)(nf * 16 + l15) * CIN + kb * 32 + lhi * 8]);
                c0[nf] = __builtin_amdgcn_mfma_f32_16x16x32_bf16(a0[kb], b, c0[nf], 0, 0, 0);
            }
        }
        #pragma unroll
        for (int j = 0; j < 4; ++j) {
            int mrow = wid * 16 + lhi * 4 + j;
            #pragma unroll
            for (int nf = 0; nf < 8; ++nf) {
                int n = nf * 16 + l15;
                float v = fmaxf(c0[nf][j] + b0[n], 0.f);
                int g = n >> 3, sub = n & 7;
                hl[mrow * 128 + (((g ^ (mrow & 15)) << 3) | sub)] = f2bf(v);
            }
        }
    }
    __syncthreads();

    // ---- gemm1: T = dinv1 * (h0 @ W1) ----
    short8 a1[4];
    #pragma unroll
    for (int kb = 0; kb < 4; ++kb) {
        int g = kb * 4 + lhi;
        a1[kb] = *reinterpret_cast<const short8*>(&hl[arow * 128 + ((g ^ (arow & 15)) << 3)]);
    }
    f32x4 c1[8];
    #pragma unroll
    for (int nf = 0; nf < 8; ++nf) c1[nf] = f32x4{0.f, 0.f, 0.f, 0.f};
    #pragma unroll
    for (int nf = 0; nf < 8; ++nf) {
        #pragma unroll
        for (int kb = 0; kb < 4; ++kb) {
            short8 b = *reinterpret_cast<const short8*>(
                &Wt1[(size_t)(nf * 16 + l15) * HN + kb * 32 + lhi * 8]);
            c1[nf] = __builtin_amdgcn_mfma_f32_16x16x32_bf16(a1[kb], b, c1[nf], 0, 0, 0);
        }
    }
    #pragma unroll
    for (int j = 0; j < 4; ++j) {
        int m = rowbase + wid * 16 + lhi * 4 + j;
        if (m >= N1) continue;
        float d = rsqrtf((float)(noff1[m + 1] - noff1[m]) + 2.f);
        #pragma unroll
        for (int nf = 0; nf < 8; ++nf) {
            int n = nf * 16 + l15;
            Tout[(size_t)m * HN + n] = f2bf(c1[nf][j] * d);
        }
    }
}

// ---------------------------------------------------------------------------
// Fused gather+GEMM (256 thr, 64-row tile, K=128): h = relu?(dv*(agg T + 2T) + gbias)
// per row (<NG, else 0), then out = [h @ Wt (+ev*Wex) (+gemmbias)] (*dinv via snoff)
template<bool GBIAS, bool EXTRA, bool GEMMBIAS, bool SCALE, bool OUTF32>
__global__ __launch_bounds__(256) void fused_gg(
    const int* __restrict__ noff, const int* __restrict__ csr,
    const ushort* __restrict__ T,
    const float* __restrict__ gbias, int NG,
    const float* __restrict__ extraVal, int extraLimit, const float* __restrict__ Wex,
    const ushort* __restrict__ Wt, const float* __restrict__ gemmbias,
    const int* __restrict__ snoff,
    void* __restrict__ dstv, int M)
{
    __shared__ ushort hl[64 * 128];
    const int tid = threadIdx.x;
    const int rowbase = blockIdx.x * 64;

    // ---- gather phase (16 lanes per node, 8 cols each) ----
    {
        const int grp = tid >> 4, ln = tid & 15;
        for (int dd = grp; dd < 64; dd += 16) {
            int i = rowbase + dd;
            short8 o = {0, 0, 0, 0, 0, 0, 0, 0};
            if (i < NG) {
                int e = noff[i], e1 = noff[i + 1];
                float dv = rsqrtf((float)(e1 - e) + 2.f);
                float acc[8] = {0.f, 0.f, 0.f, 0.f, 0.f, 0.f, 0.f, 0.f};
                for (; e + 4 <= e1; e += 4) {
                    int sa = csr[e], sb = csr[e + 1], sc = csr[e + 2], sd = csr[e + 3];
                    short8 va = *reinterpret_cast<const short8*>(T + (size_t)sa * HN + ln * 8);
                    short8 vb = *reinterpret_cast<const short8*>(T + (size_t)sb * HN + ln * 8);
                    short8 vc = *reinterpret_cast<const short8*>(T + (size_t)sc * HN + ln * 8);
                    short8 vd = *reinterpret_cast<const short8*>(T + (size_t)sd * HN + ln * 8);
                    #pragma unroll
                    for (int j = 0; j < 8; ++j)
                        acc[j] += (bf2f((ushort)va[j]) + bf2f((ushort)vb[j]))
                                + (bf2f((ushort)vc[j]) + bf2f((ushort)vd[j]));
                }
                for (; e < e1; ++e) {
                    int s = csr[e];
                    short8 v = *reinterpret_cast<const short8*>(T + (size_t)s * HN + ln * 8);
                    #pragma unroll
                    for (int j = 0; j < 8; ++j) acc[j] += bf2f((ushort)v[j]);
                }
                short8 t8 = *reinterpret_cast<const short8*>(T + (size_t)i * HN + ln * 8);
                #pragma unroll
                for (int j = 0; j < 8; ++j) {
                    float v = dv * (acc[j] + 2.f * bf2f((ushort)t8[j]));
                    if (GBIAS) v = fmaxf(v + gbias[ln * 8 + j], 0.f);
                    o[j] = (short)f2bf(v);
                }
            }
            *reinterpret_cast<short8*>(&hl[dd * 128 + ((ln ^ (dd & 15)) << 3)]) = o;
        }
    }
    __syncthreads();

    // ---- GEMM phase: 4 waves, each 16 rows x 128 cols ----
    const int wid = tid >> 6, lane = tid & 63, l15 = lane & 15, lhi = lane >> 4;
    const int arow = wid * 16 + l15;
    short8 a[4];
    #pragma unroll
    for (int kb = 0; kb < 4; ++kb) {
        int g = kb * 4 + lhi;
        a[kb] = *reinterpret_cast<const short8*>(&hl[arow * 128 + ((g ^ (arow & 15)) << 3)]);
    }
    f32x4 acc[8];
    #pragma unroll
    for (int nf = 0; nf < 8; ++nf) acc[nf] = f32x4{0.f, 0.f, 0.f, 0.f};
    #pragma unroll
    for (int nf = 0; nf < 8; ++nf) {
        #pragma unroll
        for (int kb = 0; kb < 4; ++kb) {
            short8 b = *reinterpret_cast<const short8*>(
                &Wt[(size_t)(nf * 16 + l15) * HN + kb * 32 + lhi * 8]);
            acc[nf] = __builtin_amdgcn_mfma_f32_16x16x32_bf16(a[kb], b, acc[nf], 0, 0, 0);
        }
    }
    #pragma unroll
    for (int j = 0; j < 4; ++j) {
        int m = rowbase + wid * 16 + lhi * 4 + j;
        if (m >= M) continue;
        float ev = 0.f, d = 1.f;
        if (EXTRA) ev = (m < extraLimit) ? extraVal[m] : 0.f;
        if (SCALE) d = rsqrtf((float)(snoff[m + 1] - snoff[m]) + 2.f);
        #pragma unroll
        for (int nf = 0; nf < 8; ++nf) {
            int n = nf * 16 + l15;
            float v = acc[nf][j];
            if (EXTRA)    v += ev * Wex[n];
            if (GEMMBIAS) v += gemmbias[n];
            if (SCALE)    v *= d;
            if (OUTF32) ((float*)dstv)[(size_t)m * HN + n] = v;
            else        ((ushort*)dstv)[(size_t)m * HN + n] = f2bf(v);
        }
    }
}

inline int cdiv(int a, int b) { return (a + b - 1) / b; }

} // namespace

extern "C" void kernel_launch(void* const* d_in, const int* in_sizes, int n_in,
                              void* d_out, int out_size, void* d_ws, size_t ws_size,
                              hipStream_t stream)
{
    const float* x       = (const float*)d_in[0];
    const float* W_down0 = (const float*)d_in[2];
    const float* b_down0 = (const float*)d_in[3];
    const float* W_down1 = (const float*)d_in[4];
    const float* b_down1 = (const float*)d_in[5];
    const float* W_up0   = (const float*)d_in[6];
    const float* b_up0   = (const float*)d_in[7];
    const float* W_up1   = (const float*)d_in[8];
    const float* b_up1   = (const float*)d_in[9];
    const float* W_lin   = (const float*)d_in[10];
    const float* b_lin   = (const float*)d_in[11];
    const int*   ei0     = (const int*)d_in[12];
    const int*   ei1     = (const int*)d_in[13];
    const int*   ei2     = (const int*)d_in[14];

    char* ws = (char*)d_ws;
    size_t o = 0;
    auto carve = [&](size_t bytes) { void* p = ws + o; o += (bytes + 15) & ~size_t(15); return p; };

    ushort* X     = (ushort*)carve((size_t)N0 * HN * 2);   // hosts xs during setup/L0
    ushort* T     = (ushort*)carve((size_t)N0 * HN * 2);
    ushort* Wt0   = (ushort*)carve((size_t)HN * CIN * 2);
    ushort* Wt1   = (ushort*)carve((size_t)HN * HN * 2);
    ushort* Wt2   = (ushort*)carve((size_t)HN * HN * 2);
    ushort* Wt3   = (ushort*)carve((size_t)HN * HN * 2);
    ushort* Wt4   = (ushort*)carve((size_t)HN * HN * 2);
    int*    pairs0 = (int*)carve((size_t)E0 * 4);
    int*    pairs1 = (int*)carve((size_t)E1 * 4);
    int*    blkcnt = (int*)carve((size_t)(NBLK0 * NBKT0 + NBLK1 * NBKT1) * 4);
    int*    blkoff = (int*)carve((size_t)(NBLK0 * NBKT0 + NBLK1 * NBKT1) * 4);
    int*    bktbase = (int*)carve((size_t)(NBKT0 + NBKT1 + 2) * 4);
    int*    noff0 = (int*)carve((size_t)(N0 + 1) * 4);
    int*    noff1 = (int*)carve((size_t)(N1 + 1) * 4);
    // contiguous zero block
    size_t zero_off = o;
    int*    bkttot = (int*)carve((size_t)(NBKT0 + NBKT1) * 4);
    float*  cntE   = (float*)carve((size_t)N2 * 4);
    size_t zero_bytes = o - zero_off;

    ushort* xs = X;   // xs [N0 x 64] bf16 lives in X until F2 overwrites it

    hipMemsetAsync(ws + zero_off, 0, zero_bytes, stream);

    // ---- setup ----
    setup_small<<<dim3(cdiv(2 * E2, 256), 2), 256, 0, stream>>>(
        ei2, cntE, W_down0, W_down1, W_up0, W_up1, W_lin, Wt0, Wt1, Wt2, Wt3, Wt4);
    count_pass<<<NBLK0 + NBLK1, 512, 0, stream>>>(ei0, ei1, blkcnt, bkttot);
    scanB<<<2, 64, 0, stream>>>(bkttot, bktbase);
    scanC<<<NBKT0 + NBKT1, 64, 0, stream>>>(blkcnt, bktbase, blkoff);
    partition_pass<<<NBLK0 + NBLK1, 512, 0, stream>>>(ei0, ei1, blkoff, pairs0, pairs1);
    sort_pass<<<NBKT0 + NBKT1, 256, 0, stream>>>(pairs0, pairs1, bktbase,
                                                 noff0, noff1, x, xs);

    // ---- F01: xs --agg0--> gemm0(relu) --> gemm1(*dinv1) --> T[0:N1] ----
    fused_l0<<<cdiv(N1, 64), 256, 0, stream>>>(
        noff0, pairs0, xs, Wt0, b_down0, Wt1, noff1, T);

    // ---- F2: T --agg1(relu,b_down1; rows<N2)--> gemm(W_up0 + cntE*Wex, *dinv1) --> X ----
    fused_gg<true, true, false, true, false><<<cdiv(N1, 64), 256, 0, stream>>>(
        noff1, pairs1, T, b_down1, N2,
        cntE, N2, W_up0 + 128 * HN, Wt2, nullptr, noff1, X, N1);

    // ---- F3: X --agg1(relu,b_up0; rows<N1)--> gemm(W_up1 + cntE*Wex, *dinv0) --> T ----
    fused_gg<true, true, false, true, false><<<cdiv(N0, 64), 256, 0, stream>>>(
        noff1, pairs1, X, b_up0, N1,
        cntE, N2, W_up1 + 128 * HN, Wt3, nullptr, noff0, T, N0);

    // ---- F4: T --agg0(relu,b_up1)--> gemm(W_lin + b_lin) --> d_out (f32) ----
    fused_gg<true, false, true, false, true><<<cdiv(N0, 64), 256, 0, stream>>>(
        noff0, pairs0, T, b_up1, N0,
        nullptr, 0, nullptr, Wt4, b_lin, nullptr, d_out, N0);
}